// Round 5
// baseline (115.886 us; speedup 1.0000x reference)
//
#include <hip/hip_runtime.h>
#include <hip/hip_cooperative_groups.h>

namespace cg = cooperative_groups;

// M[b,i,j] (16 x 256 x 256):
//   a=i>>4, c=i&15, p=j>>4, q=j&15
//   off-diag (a<p, c<q, edge(a,p) and edge(c,q) present in BOTH graphs):
//     M = P1[a,c] + P2[p,c] + P2[a,q] + P1[p,q]
//   diag (i==j): += Mp[a,c]
// P_l = F_src^T relu(lam_l+lam_l^T) F_tgt (16x16/batch), Mp = U_src^T U_tgt.
//
// ONE cooperative kernel, grid 256:
//   phase A (blk = b,lsel,islice): T_l = relu(lam+lam^T) F_tgt -> ws,
//     stored TRANSPOSED [b][l][v][d] so phase B vec-loads over d.
//   grid.sync()
//   phase B (blk = b,a): P tables from ws (b128 LDS loop) + fill 16 rows.

#define LS 132   // padded stride: (132*x + d) % 32 = (4x+d)%32 -> <=2-way (free)
#define TS 17    // P-table stride

__device__ __forceinline__ int edge_idx(int a, int p) {
    // strict upper triangle of 16x16, row-major (triu_indices(16, k=1))
    return (a * (31 - a)) / 2 + (p - a - 1);
}

__global__ __launch_bounds__(256) void kFused(
    const int* __restrict__ Asrc, const int* __restrict__ Atgt,
    const float* __restrict__ Fsrc, const float* __restrict__ Ftgt,
    const float* __restrict__ Usrc, const float* __restrict__ Utgt,
    const float* __restrict__ lam1, const float* __restrict__ lam2,
    float* __restrict__ ws, float* __restrict__ out)
{
    __shared__ float sA[16 * LS];   // A: lam rows   | B: T1t [v][d]
    __shared__ float sB[16 * LS];   // A: lam cols   | B: T2t [v][d]
    __shared__ float sC[16 * LS];   // A: FtT [v][j] | B: FsT [u][d]
    __shared__ float sU[512];       // Us | Ut
    __shared__ float sP1[16 * TS], sP2[16 * TS], sMp[256];
    __shared__ int   smask[120];

    const int blk = blockIdx.x;
    const int t   = threadIdx.x;

    // ================= Phase A: T[b][l][v][i] ============================
    {
        const int b    = blk >> 4;
        const int lsel = (blk >> 3) & 1;
        const int i0   = (blk & 7) << 4;
        const float* lam = lsel ? lam2 : lam1;

        // rows: sA[il*LS + j] = lam[(i0+il)*128 + j]   (float4 coalesced)
        const float4* rp = (const float4*)(lam + i0 * 128);
#pragma unroll
        for (int it = 0; it < 2; ++it) {
            const int k = t + it * 256;              // [0,512) float4s
            const int il = k >> 5, j4 = k & 31;
            *(float4*)(&sA[il * LS + j4 * 4]) = rp[il * 32 + j4];
        }
        // cols: sB[il*LS + j] = lam[j*128 + i0+il]    (64B-contig gather)
#pragma unroll
        for (int it = 0; it < 8; ++it) {
            const int k = t + it * 256;              // [0,2048)
            const int il = k & 15, j = k >> 4;
            sB[il * LS + j] = lam[j * 128 + i0 + il];
        }
        // FtT: sC[v*LS + j] = Ftgt[b][j][v]          (transpose via LDS)
        const float4* fp = (const float4*)(Ftgt + b * 2048);
#pragma unroll
        for (int it = 0; it < 2; ++it) {
            const int k = t + it * 256;              // float4 = Ft[j][v0..v0+3]
            const int j = k >> 2, v0 = (k & 3) * 4;
            const float4 f = fp[k];
            sC[(v0 + 0) * LS + j] = f.x;
            sC[(v0 + 1) * LS + j] = f.y;
            sC[(v0 + 2) * LS + j] = f.z;
            sC[(v0 + 3) * LS + j] = f.w;
        }
        __syncthreads();

        const int v = t >> 4, il = t & 15;           // il fast -> coalesced ws
        float acc = 0.f;
#pragma unroll 8
        for (int j0 = 0; j0 < 128; j0 += 4) {
            const float4 r = *(const float4*)(&sA[il * LS + j0]);
            const float4 c = *(const float4*)(&sB[il * LS + j0]);
            const float4 f = *(const float4*)(&sC[v * LS + j0]);
            acc = fmaf(fmaxf(r.x + c.x, 0.f), f.x, acc);
            acc = fmaf(fmaxf(r.y + c.y, 0.f), f.y, acc);
            acc = fmaf(fmaxf(r.z + c.z, 0.f), f.z, acc);
            acc = fmaf(fmaxf(r.w + c.w, 0.f), f.w, acc);
        }
        // ws: T[b][l][v][d] at ((b*2+l)*16 + v)*128 + i0 + il
        ws[((b * 2 + lsel) * 16 + v) * 128 + i0 + il] = acc;
    }

    cg::this_grid().sync();

    // ================= Phase B: blk = (b, a) =============================
    {
        const int b = blk >> 4;
        const int a = blk & 15;

        // T tables, already [v][d]: straight float4 copy into padded LDS
        const float4* T1g = (const float4*)(ws + (b * 2 + 0) * 2048);
        const float4* T2g = (const float4*)(ws + (b * 2 + 1) * 2048);
#pragma unroll
        for (int it = 0; it < 2; ++it) {
            const int k = t + it * 256;              // [0,512) float4s
            const int v = k >> 5, d4 = (k & 31) * 4;
            *(float4*)(&sA[v * LS + d4]) = T1g[k];
            *(float4*)(&sB[v * LS + d4]) = T2g[k];
        }
        // FsT: sC[u*LS + d] = Fsrc[b][d][u]          (transpose via LDS)
        const float4* fp = (const float4*)(Fsrc + b * 2048);
#pragma unroll
        for (int it = 0; it < 2; ++it) {
            const int k = t + it * 256;
            const int d = k >> 2, u0 = (k & 3) * 4;
            const float4 f = fp[k];
            sC[(u0 + 0) * LS + d] = f.x;
            sC[(u0 + 1) * LS + d] = f.y;
            sC[(u0 + 2) * LS + d] = f.z;
            sC[(u0 + 3) * LS + d] = f.w;
        }
        if (t < 64)       ((float4*)sU)[t] = ((const float4*)(Usrc + b * 256))[t];
        else if (t < 128) ((float4*)sU)[t] = ((const float4*)(Utgt + b * 256))[t - 64];
        if (t < 120) smask[t] = (Asrc[b * 120 + t] > 0) && (Atgt[b * 120 + t] > 0);
        __syncthreads();

        // tables: P_l[u][v] = sum_d FsT[u][d] * Tlt[v][d];  Mp[u][v]
        {
            const int u = t >> 4, v = t & 15;
            float p1 = 0.f, p2 = 0.f;
#pragma unroll 8
            for (int d0 = 0; d0 < 128; d0 += 4) {
                const float4 fs = *(const float4*)(&sC[u * LS + d0]);
                const float4 t1 = *(const float4*)(&sA[v * LS + d0]);
                const float4 t2 = *(const float4*)(&sB[v * LS + d0]);
                p1 = fmaf(fs.x, t1.x, p1);  p2 = fmaf(fs.x, t2.x, p2);
                p1 = fmaf(fs.y, t1.y, p1);  p2 = fmaf(fs.y, t2.y, p2);
                p1 = fmaf(fs.z, t1.z, p1);  p2 = fmaf(fs.z, t2.z, p2);
                p1 = fmaf(fs.w, t1.w, p1);  p2 = fmaf(fs.w, t2.w, p2);
            }
            float mp = 0.f;
#pragma unroll
            for (int d = 0; d < 16; ++d)
                mp = fmaf(sU[(d << 4) | u], sU[256 + ((d << 4) | v)], mp);
            sP1[u * TS + v] = p1;
            sP2[u * TS + v] = p2;
            sMp[t] = mp;                              // Mp[u][v] at (u<<4)|v
        }
        __syncthreads();

        // fill rows r = a*16 + c; coalesced float4 stores
        const int j0 = (t & 63) << 2;
        const int p  = j0 >> 4;
        const bool condA = (a < p) && (smask[edge_idx(a, p)] != 0);
        float* outR = out + ((size_t)b << 16) + (a << 12);
#pragma unroll
        for (int rr = 0; rr < 4; ++rr) {
            const int c = (t >> 6) + (rr << 2);
            const int r = (a << 4) | c;
            const float cpart = sP1[a * TS + c] + sP2[p * TS + c];
            float4 vec;
            float* vv = (float*)&vec;
#pragma unroll
            for (int s = 0; s < 4; ++s) {
                const int j = j0 + s, q = j & 15;
                float x = 0.f;
                if (condA && (c < q) && (smask[edge_idx(c, q)] != 0))
                    x = cpart + sP2[a * TS + q] + sP1[p * TS + q];
                if (r == j) x += sMp[r];
                vv[s] = x;
            }
            *(float4*)(outR + (c << 8) + j0) = vec;
        }
    }
}

extern "C" void kernel_launch(void* const* d_in, const int* in_sizes, int n_in,
                              void* d_out, int out_size, void* d_ws, size_t ws_size,
                              hipStream_t stream) {
    const int*   A_src = (const int*)d_in[0];
    const int*   A_tgt = (const int*)d_in[1];
    const float* F_src = (const float*)d_in[2];
    const float* F_tgt = (const float*)d_in[3];
    const float* U_src = (const float*)d_in[4];
    const float* U_tgt = (const float*)d_in[5];
    const float* lam1  = (const float*)d_in[6];
    const float* lam2  = (const float*)d_in[7];
    float* out = (float*)d_out;
    float* ws  = (float*)d_ws;   // 65536 floats = 256 KB used

    void* args[] = {
        (void*)&A_src, (void*)&A_tgt, (void*)&F_src, (void*)&F_tgt,
        (void*)&U_src, (void*)&U_tgt, (void*)&lam1, (void*)&lam2,
        (void*)&ws, (void*)&out
    };
    hipLaunchCooperativeKernel((const void*)kFused, dim3(256), dim3(256),
                               args, 0, stream);
}

// Round 6
// 77.595 us; speedup vs baseline: 1.4935x; 1.4935x over previous
//
#include <hip/hip_runtime.h>

// M[b,i,j] (16 x 256 x 256):
//   a=i>>4, c=i&15, p=j>>4, q=j&15
//   off-diag (a<p, c<q, edge(a,p) and edge(c,q) present in BOTH graphs):
//     M = P1[a,c] + P2[p,c] + P2[a,q] + P1[p,q]
//   diag (i==j): += Mp[a,c]
// P_l = F_src^T relu(lam_l+lam_l^T) F_tgt (16x16/batch), Mp = U_src^T U_tgt.
//
// kA: T_l = relu(lam+lam^T) F_tgt -> ws TRANSPOSED [b][l][v][d]
//     (grid 256 = b,lsel,islice; all-b128 inner loop).
// kB: P tables from ws (pure b128 LDS loop) + output fill (grid 256 = b,a).

#define LS 132   // padded stride: (132*x + d) % 32 = (4x+d)%32 -> <=2-way (free)
#define TS 17    // P-table stride

__device__ __forceinline__ int edge_idx(int a, int p) {
    // strict upper triangle of 16x16, row-major (triu_indices(16, k=1))
    return (a * (31 - a)) / 2 + (p - a - 1);
}

// ---------------------------------------------------------------------------
// kA: T[b][l][v][i] = sum_j relu(lam[i][j]+lam[j][i]) * Ftgt[b][j][v]
// grid 256: b = blk>>4, lsel = (blk>>3)&1, i0 = (blk&7)*16
// ---------------------------------------------------------------------------
__global__ __launch_bounds__(256) void kA(
    const float* __restrict__ Ftgt,
    const float* __restrict__ lam1, const float* __restrict__ lam2,
    float* __restrict__ ws)
{
    __shared__ float sRow[16 * LS];   // lam rows  [il][j]
    __shared__ float sCol[16 * LS];   // lam cols  [il][j]
    __shared__ float sFtT[16 * LS];   // Ft^T      [v][j]

    const int blk  = blockIdx.x;
    const int b    = blk >> 4;
    const int lsel = (blk >> 3) & 1;
    const int i0   = (blk & 7) << 4;
    const int t    = threadIdx.x;

    const float* lam = lsel ? lam2 : lam1;

    // rows: sRow[il*LS + j] = lam[(i0+il)*128 + j]   (float4 coalesced)
    const float4* rp = (const float4*)(lam + i0 * 128);
#pragma unroll
    for (int it = 0; it < 2; ++it) {
        const int k = t + it * 256;              // [0,512) float4s
        const int il = k >> 5, j4 = k & 31;
        *(float4*)(&sRow[il * LS + j4 * 4]) = rp[il * 32 + j4];
    }
    // cols: sCol[il*LS + j] = lam[j*128 + i0+il]    (64B-contig gather, L2-hot)
#pragma unroll
    for (int it = 0; it < 8; ++it) {
        const int k = t + it * 256;              // [0,2048)
        const int il = k & 15, j = k >> 4;
        sCol[il * LS + j] = lam[j * 128 + i0 + il];
    }
    // FtT: sFtT[v*LS + j] = Ftgt[b][j][v]          (transpose via LDS)
    const float4* fp = (const float4*)(Ftgt + b * 2048);
#pragma unroll
    for (int it = 0; it < 2; ++it) {
        const int k = t + it * 256;              // float4 = Ft[j][v0..v0+3]
        const int j = k >> 2, v0 = (k & 3) * 4;
        const float4 f = fp[k];
        sFtT[(v0 + 0) * LS + j] = f.x;
        sFtT[(v0 + 1) * LS + j] = f.y;
        sFtT[(v0 + 2) * LS + j] = f.z;
        sFtT[(v0 + 3) * LS + j] = f.w;
    }
    __syncthreads();

    const int v = t >> 4, il = t & 15;           // il fast -> coalesced ws write
    float acc = 0.f;
#pragma unroll 8
    for (int j0 = 0; j0 < 128; j0 += 4) {
        const float4 r = *(const float4*)(&sRow[il * LS + j0]);
        const float4 c = *(const float4*)(&sCol[il * LS + j0]);
        const float4 f = *(const float4*)(&sFtT[v * LS + j0]);
        acc = fmaf(fmaxf(r.x + c.x, 0.f), f.x, acc);
        acc = fmaf(fmaxf(r.y + c.y, 0.f), f.y, acc);
        acc = fmaf(fmaxf(r.z + c.z, 0.f), f.z, acc);
        acc = fmaf(fmaxf(r.w + c.w, 0.f), f.w, acc);
    }
    // ws: T[b][l][v][d] at ((b*2+l)*16 + v)*128 + i0 + il
    ws[((b * 2 + lsel) * 16 + v) * 128 + i0 + il] = acc;
}

// ---------------------------------------------------------------------------
// kB: per-block P1/P2/Mp tables (redundant across the 16 row-groups of a
// batch — cheap, fully parallel), then fill 16 output rows.
// grid 256: b = blk>>4, a = blk&15.
// ---------------------------------------------------------------------------
__global__ __launch_bounds__(256) void kB(
    const int* __restrict__ Asrc, const int* __restrict__ Atgt,
    const float* __restrict__ Fsrc,
    const float* __restrict__ Usrc, const float* __restrict__ Utgt,
    const float* __restrict__ ws, float* __restrict__ out)
{
    __shared__ float sT1[16 * LS];   // T1^T [v][d]
    __shared__ float sT2[16 * LS];   // T2^T [v][d]
    __shared__ float sFs[16 * LS];   // Fs^T [u][d]
    __shared__ float sU[512];        // Us | Ut
    __shared__ float sP1[16 * TS], sP2[16 * TS], sMp[256];
    __shared__ int   smask[120];

    const int blk = blockIdx.x;
    const int b   = blk >> 4;
    const int a   = blk & 15;
    const int t   = threadIdx.x;

    // T tables, already [v][d] in ws: straight float4 copy into padded LDS
    const float4* T1g = (const float4*)(ws + (b * 2 + 0) * 2048);
    const float4* T2g = (const float4*)(ws + (b * 2 + 1) * 2048);
#pragma unroll
    for (int it = 0; it < 2; ++it) {
        const int k = t + it * 256;              // [0,512) float4s
        const int v = k >> 5, d4 = (k & 31) * 4;
        *(float4*)(&sT1[v * LS + d4]) = T1g[k];
        *(float4*)(&sT2[v * LS + d4]) = T2g[k];
    }
    // FsT: sFs[u*LS + d] = Fsrc[b][d][u]          (transpose via LDS)
    const float4* fp = (const float4*)(Fsrc + b * 2048);
#pragma unroll
    for (int it = 0; it < 2; ++it) {
        const int k = t + it * 256;
        const int d = k >> 2, u0 = (k & 3) * 4;
        const float4 f = fp[k];
        sFs[(u0 + 0) * LS + d] = f.x;
        sFs[(u0 + 1) * LS + d] = f.y;
        sFs[(u0 + 2) * LS + d] = f.z;
        sFs[(u0 + 3) * LS + d] = f.w;
    }
    if (t < 64)       ((float4*)sU)[t] = ((const float4*)(Usrc + b * 256))[t];
    else if (t < 128) ((float4*)sU)[t] = ((const float4*)(Utgt + b * 256))[t - 64];
    if (t < 120) smask[t] = (Asrc[b * 120 + t] > 0) && (Atgt[b * 120 + t] > 0);
    __syncthreads();

    // tables: P_l[u][v] = sum_d FsT[u][d] * Tlt[v][d];  Mp[u][v]
    {
        const int u = t >> 4, v = t & 15;
        float p1 = 0.f, p2 = 0.f;
#pragma unroll 8
        for (int d0 = 0; d0 < 128; d0 += 4) {
            const float4 fs = *(const float4*)(&sFs[u * LS + d0]);
            const float4 t1 = *(const float4*)(&sT1[v * LS + d0]);
            const float4 t2 = *(const float4*)(&sT2[v * LS + d0]);
            p1 = fmaf(fs.x, t1.x, p1);  p2 = fmaf(fs.x, t2.x, p2);
            p1 = fmaf(fs.y, t1.y, p1);  p2 = fmaf(fs.y, t2.y, p2);
            p1 = fmaf(fs.z, t1.z, p1);  p2 = fmaf(fs.z, t2.z, p2);
            p1 = fmaf(fs.w, t1.w, p1);  p2 = fmaf(fs.w, t2.w, p2);
        }
        float mp = 0.f;
#pragma unroll
        for (int d = 0; d < 16; ++d)
            mp = fmaf(sU[(d << 4) | u], sU[256 + ((d << 4) | v)], mp);
        sP1[u * TS + v] = p1;
        sP2[u * TS + v] = p2;
        sMp[t] = mp;                              // Mp[u][v] at (u<<4)|v
    }
    __syncthreads();

    // fill rows r = a*16 + c; coalesced float4 stores
    const int j0 = (t & 63) << 2;
    const int p  = j0 >> 4;
    const bool condA = (a < p) && (smask[edge_idx(a, p)] != 0);
    float* outR = out + ((size_t)b << 16) + (a << 12);
#pragma unroll
    for (int rr = 0; rr < 4; ++rr) {
        const int c = (t >> 6) + (rr << 2);
        const int r = (a << 4) | c;
        const float cpart = sP1[a * TS + c] + sP2[p * TS + c];
        float4 vec;
        float* vv = (float*)&vec;
#pragma unroll
        for (int s = 0; s < 4; ++s) {
            const int j = j0 + s, q = j & 15;
            float x = 0.f;
            if (condA && (c < q) && (smask[edge_idx(c, q)] != 0))
                x = cpart + sP2[a * TS + q] + sP1[p * TS + q];
            if (r == j) x += sMp[r];
            vv[s] = x;
        }
        *(float4*)(outR + (c << 8) + j0) = vec;
    }
}

extern "C" void kernel_launch(void* const* d_in, const int* in_sizes, int n_in,
                              void* d_out, int out_size, void* d_ws, size_t ws_size,
                              hipStream_t stream) {
    const int*   A_src = (const int*)d_in[0];
    const int*   A_tgt = (const int*)d_in[1];
    const float* F_src = (const float*)d_in[2];
    const float* F_tgt = (const float*)d_in[3];
    const float* U_src = (const float*)d_in[4];
    const float* U_tgt = (const float*)d_in[5];
    const float* lam1  = (const float*)d_in[6];
    const float* lam2  = (const float*)d_in[7];
    float* out = (float*)d_out;
    float* ws  = (float*)d_ws;   // 65536 floats = 256 KB used

    kA<<<256, 256, 0, stream>>>(F_tgt, lam1, lam2, ws);
    kB<<<256, 256, 0, stream>>>(A_src, A_tgt, F_src, U_src, U_tgt, ws, out);
}